// Round 1
// baseline (889.563 us; speedup 1.0000x reference)
//
#include <hip/hip_runtime.h>
#include <math.h>

#define EDIM 4096
#define BS 32
#define NT 64      // output columns per tile (= wave width)
#define KSPLIT 4   // K-split blocks per tile
#define NWAVES 4   // waves per block (in-block K split)
#define BLK 256

__device__ __forceinline__ float relu_f(float x) { return x > 0.f ? x : 0.f; }

// ---------------------------------------------------------------------------
// prep: A0 = relu(BN(image)) stored feature-major [E][32]; v = relu(fs_bn_b[E:2E]);
// flag = any(v != 0)  (text half of BN(concat) is exactly fs_bn_b[E:] since the
// tiled text row is constant over the batch -> (x-mu)==0).
// ---------------------------------------------------------------------------
__global__ void __launch_bounds__(BLK) prep_kernel(
    const float* __restrict__ img, const float* __restrict__ bng,
    const float* __restrict__ bnb, float* __restrict__ act0,
    float* __restrict__ vvec, int* __restrict__ flag)
{
  int n = blockIdx.x * BLK + threadIdx.x;  // 0..EDIM-1
  float bv = bnb[EDIM + n];
  float vv = relu_f(bv);
  vvec[n] = vv;
  if (vv != 0.f) atomicOr(flag, 1);

  float s = 0.f, s2 = 0.f;
  for (int r = 0; r < BS; ++r) {
    float x = img[(size_t)r * EDIM + n];
    s += x; s2 += x * x;
  }
  float mean = s * (1.f / BS);
  float var  = s2 * (1.f / BS) - mean * mean;
  float sc = bng[n] * rsqrtf(var + 1e-5f);
  float sh = bnb[n] - mean * sc;
  for (int r = 0; r < BS; ++r) {
    float x = img[(size_t)r * EDIM + n];
    act0[(size_t)n * BS + r] = relu_f(x * sc + sh);
  }
}

// ---------------------------------------------------------------------------
// One GEMM stage: OUT[r][n] = sum_k Ain[k][r] * W[k][n], K split 16-way
// (4 waves x 4 blocks), combined with fp32 atomics; last block per 64-col tile
// applies the epilogue:
//   mode 0: +bias (fs; optional lower-half text contribution) -> dst[n][r]
//   mode 1: +bias -> batch-BN -> relu -> dst[n][r]
//   mode 2: +bias -> sigmoid -> dst row-major [r][EDIM]
//   mode 3: +bias + residual[n][r] -> dst[n][r]
// ---------------------------------------------------------------------------
__global__ void __launch_bounds__(BLK) mm_stage(
    const float* __restrict__ W, const float* __restrict__ Ain,
    const float* __restrict__ bias,
    const float* __restrict__ bng, const float* __restrict__ bnb,
    const float* __restrict__ res,
    const float* __restrict__ Wlow, const float* __restrict__ vvec,
    const int* __restrict__ flag,
    float* __restrict__ acc, int* __restrict__ counter,
    float* __restrict__ dst,
    int K, int N, int mode)
{
  const int tid  = threadIdx.x;
  const int bx   = blockIdx.x;
  const int tile = bx >> 2;
  const int ks   = bx & (KSPLIT - 1);
  const int wv   = __builtin_amdgcn_readfirstlane(tid >> 6);
  const int lane = tid & 63;
  const int n    = tile * NT + lane;
  const int kchunk = K / (KSPLIT * NWAVES);
  const int k0     = (ks * NWAVES + wv) * kchunk;

  float racc[BS];
#pragma unroll
  for (int r = 0; r < BS; ++r) racc[r] = 0.f;

  const float* wp = W + (size_t)k0 * N + n;
  const float* ap = Ain + (size_t)k0 * BS;

#pragma unroll 4
  for (int k = 0; k < kchunk; ++k) {
    float wval = wp[(size_t)k * N];          // coalesced: 64 lanes x 4B = 2 lines
    const float* arow = ap + (size_t)k * BS; // wave-uniform -> scalar loads
#pragma unroll
    for (int r = 0; r < BS; ++r) racc[r] = fmaf(arow[r], wval, racc[r]);
  }

  // fs lower half: only if relu(fs_bn_b[E:]) has any nonzero (data-dependent,
  // uniform branch; zero for the given inputs -> skipped, no 64MB read).
  if (Wlow != nullptr) {
    if (*flag) {
      float cpart = 0.f;
      const float* wl = Wlow + (size_t)k0 * N + n;
      for (int k = 0; k < kchunk; ++k)
        cpart = fmaf(vvec[k0 + k], wl[(size_t)k * N], cpart);
#pragma unroll
      for (int r = 0; r < BS; ++r) racc[r] += cpart;
    }
  }

  // intra-block reduce across the 4 waves
  __shared__ float sred[NWAVES][NT][BS];
#pragma unroll
  for (int r = 0; r < BS; r += 4)
    *(float4*)&sred[wv][lane][r] = make_float4(racc[r], racc[r+1], racc[r+2], racc[r+3]);
  __syncthreads();

  const int c  = tid >> 2;          // column within tile (0..63)
  const int rb = (tid & 3) * 8;     // row base (0,8,16,24)
  float tot[8];
#pragma unroll
  for (int u = 0; u < 8; ++u)
    tot[u] = sred[0][c][rb+u] + sred[1][c][rb+u] + sred[2][c][rb+u] + sred[3][c][rb+u];

  const int col = tile * NT + c;
  float* ga = acc + (size_t)col * BS + rb;
#pragma unroll
  for (int u = 0; u < 8; ++u) atomicAdd(ga + u, tot[u]);

  __threadfence();
  __syncthreads();
  __shared__ int s_last;
  if (tid == 0) {
    int old = atomicAdd(counter + tile, 1);
    s_last = (old == KSPLIT - 1) ? 1 : 0;
  }
  __syncthreads();
  if (!s_last) return;

  // finishing block: re-read completed sums coherently (bypass L1/L2)
  float val[8];
#pragma unroll
  for (int u = 0; u < 8; ++u)
    val[u] = __hip_atomic_load(ga + u, __ATOMIC_RELAXED, __HIP_MEMORY_SCOPE_AGENT);

  const float bb = bias[col];
#pragma unroll
  for (int u = 0; u < 8; ++u) val[u] += bb;

  if (mode == 1) {
    __shared__ float sps[NT][4], sps2[NT][4], ssc[NT], ssh[NT];
    float p = 0.f, p2 = 0.f;
#pragma unroll
    for (int u = 0; u < 8; ++u) { p += val[u]; p2 += val[u] * val[u]; }
    sps[c][tid & 3] = p; sps2[c][tid & 3] = p2;
    __syncthreads();
    if (tid < NT) {
      float s  = sps[tid][0] + sps[tid][1] + sps[tid][2] + sps[tid][3];
      float s2 = sps2[tid][0] + sps2[tid][1] + sps2[tid][2] + sps2[tid][3];
      float mean = s * (1.f / BS);
      float var  = s2 * (1.f / BS) - mean * mean;
      float sc = bng[tile * NT + tid] * rsqrtf(var + 1e-5f);
      ssc[tid] = sc;
      ssh[tid] = bnb[tile * NT + tid] - mean * sc;
    }
    __syncthreads();
    float sc = ssc[c], sh = ssh[c];
    float* dp = dst + (size_t)col * BS + rb;
#pragma unroll
    for (int u = 0; u < 8; ++u) dp[u] = relu_f(val[u] * sc + sh);
  } else if (mode == 2) {
#pragma unroll
    for (int u = 0; u < 8; ++u) {
      float g = 1.f / (1.f + __expf(-val[u]));
      dst[(size_t)(rb + u) * EDIM + col] = g;   // row-major for final kernel
    }
  } else if (mode == 3) {
    const float* rp = res + (size_t)col * BS + rb;
    float* dp = dst + (size_t)col * BS + rb;
#pragma unroll
    for (int u = 0; u < 8; ++u) dp[u] = val[u] + rp[u];
  } else {
    float* dp = dst + (size_t)col * BS + rb;
#pragma unroll
    for (int u = 0; u < 8; ++u) dp[u] = val[u];
  }
}

// ---------------------------------------------------------------------------
// final: out[j][r][e] = img[r][e]*g[r][e] + ff[r][e]*(1-g[r][e]), identical for
// all j -> compute once, write 8 j-copies per block (4 j-groups x 64 e-tiles).
// ---------------------------------------------------------------------------
__global__ void __launch_bounds__(BLK) final_kernel(
    const float* __restrict__ img, const float* __restrict__ grm,
    const float* __restrict__ fft, float* __restrict__ out)
{
  __shared__ float sff[BS][NT];   // transposed stage: read [e][r] -> serve [r][e]
  const int tid  = threadIdx.x;
  const int tile = blockIdx.x & 63;
  const int jg   = blockIdx.x >> 6;
  const int c  = tid >> 2;
  const int rb = (tid & 3) * 8;
  const float* src = fft + (size_t)(tile * NT + c) * BS + rb;
#pragma unroll
  for (int u = 0; u < 8; ++u) sff[rb + u][c] = src[u];
  __syncthreads();

  const int le = tid & 63, rg = tid >> 6;
  const int e  = tile * NT + le;
#pragma unroll
  for (int rr = 0; rr < 8; ++rr) {
    int r = rr * 4 + rg;
    float gv = grm[(size_t)r * EDIM + e];
    float iv = img[(size_t)r * EDIM + e];
    float o  = iv * gv + sff[r][le] * (1.f - gv);
#pragma unroll
    for (int jj = 0; jj < 8; ++jj) {
      int j = jg * 8 + jj;
      out[((size_t)(j * BS + r)) * EDIM + e] = o;
    }
  }
}

// ---------------------------------------------------------------------------
extern "C" void kernel_launch(void* const* d_in, const int* in_sizes, int n_in,
                              void* d_out, int out_size, void* d_ws, size_t ws_size,
                              hipStream_t stream)
{
  const float* img    = (const float*)d_in[0];
  // d_in[1] text_features: provably unused (BN of constant batch rows)
  const float* fs_bng = (const float*)d_in[2];
  const float* fs_bnb = (const float*)d_in[3];
  const float* fs_w   = (const float*)d_in[4];
  const float* fs_b   = (const float*)d_in[5];
  const float* gt_w1  = (const float*)d_in[6];
  const float* gt_b1  = (const float*)d_in[7];
  const float* gt_bng = (const float*)d_in[8];
  const float* gt_bnb = (const float*)d_in[9];
  const float* gt_w2  = (const float*)d_in[10];
  const float* gt_b2  = (const float*)d_in[11];
  const float* ee_w1  = (const float*)d_in[12];
  const float* ee_b1  = (const float*)d_in[13];
  const float* ee_bng = (const float*)d_in[14];
  const float* ee_bnb = (const float*)d_in[15];
  const float* ee_w2  = (const float*)d_in[16];
  const float* ee_b2  = (const float*)d_in[17];
  float* out = (float*)d_out;

  float* w = (float*)d_ws;
  size_t o = 0;
  float* acc_fs = w + o; o += (size_t)EDIM * BS;
  float* acc_g1 = w + o; o += (size_t)EDIM * BS;
  float* acc_g2 = w + o; o += (size_t)EDIM * BS;
  float* acc_ea[3]; for (int i = 0; i < 3; ++i) { acc_ea[i] = w + o; o += (size_t)(EDIM/2) * BS; }
  float* acc_eb[3]; for (int i = 0; i < 3; ++i) { acc_eb[i] = w + o; o += (size_t)EDIM * BS; }
  int* counters = (int*)(w + o); o += 1024;   // 9 stages x 64 tiles + flag, zeroed
  int* flag = counters + 960;
  size_t zero_bytes = o * sizeof(float);
  float* act0 = w + o; o += (size_t)EDIM * BS;
  float* vvec = w + o; o += EDIM;
  float* fbuf = w + o; o += (size_t)EDIM * BS;
  float* hgb  = w + o; o += (size_t)EDIM * BS;
  float* gbuf = w + o; o += (size_t)EDIM * BS;
  float* he[3];  for (int i = 0; i < 3; ++i) { he[i]  = w + o; o += (size_t)(EDIM/2) * BS; }
  float* ffb[3]; for (int i = 0; i < 3; ++i) { ffb[i] = w + o; o += (size_t)EDIM * BS; }

  hipMemsetAsync(d_ws, 0, zero_bytes, stream);

  prep_kernel<<<EDIM / BLK, BLK, 0, stream>>>(img, fs_bng, fs_bnb, act0, vvec, flag);

  // fs: f = A0 @ fs_w[:E] + fs_b (+ optional text-bias term via Wlow)
  mm_stage<<<(EDIM / NT) * KSPLIT, BLK, 0, stream>>>(
      fs_w, act0, fs_b, nullptr, nullptr, nullptr,
      fs_w + (size_t)EDIM * EDIM, vvec, flag,
      acc_fs, counters + 0, fbuf, EDIM, EDIM, 0);

  // gating
  mm_stage<<<(EDIM / NT) * KSPLIT, BLK, 0, stream>>>(
      gt_w1, fbuf, gt_b1, gt_bng, gt_bnb, nullptr, nullptr, nullptr, nullptr,
      acc_g1, counters + 64, hgb, EDIM, EDIM, 1);
  mm_stage<<<(EDIM / NT) * KSPLIT, BLK, 0, stream>>>(
      gt_w2, hgb, gt_b2, nullptr, nullptr, nullptr, nullptr, nullptr, nullptr,
      acc_g2, counters + 128, gbuf, EDIM, EDIM, 2);

  // 3 error-encoding residual blocks
  const float* ffin = fbuf;
  for (int i = 0; i < 3; ++i) {
    mm_stage<<<((EDIM / 2) / NT) * KSPLIT, BLK, 0, stream>>>(
        ee_w1 + (size_t)i * EDIM * (EDIM / 2), ffin,
        ee_b1 + (size_t)i * (EDIM / 2), ee_bng + (size_t)i * (EDIM / 2),
        ee_bnb + (size_t)i * (EDIM / 2),
        nullptr, nullptr, nullptr, nullptr,
        acc_ea[i], counters + 192 + i * 128, he[i], EDIM, EDIM / 2, 1);
    mm_stage<<<(EDIM / NT) * KSPLIT, BLK, 0, stream>>>(
        ee_w2 + (size_t)i * (EDIM / 2) * EDIM, he[i],
        ee_b2 + (size_t)i * EDIM, nullptr, nullptr, ffin,
        nullptr, nullptr, nullptr,
        acc_eb[i], counters + 256 + i * 128, ffb[i], EDIM / 2, EDIM, 3);
    ffin = ffb[i];
  }

  final_kernel<<<64 * 4, BLK, 0, stream>>>(img, gbuf, ffin, out);
}